// Round 13
// baseline (2772.372 us; speedup 1.0000x reference)
//
#include <hip/hip_runtime.h>

// MFMA split-FP16 jet-propagation PINN.
// Jet comps: 0:val 1:x 2:y 3:t 4:xx 5:xy 6:yy 7:xt 8:yt 9:xxx 10:xxy 11:xyy 12:yyy
// J in LDS: rows m = sample*16 + comp (13 used), k = hidden neuron; f16 hi+lo planes.
// Row layout: 32 chunks of 8 f16 (16 B); phys chunk = logical ^ (m&15)  (bank swizzle).
// Per layer: U = J * W^T via mfma_f32_16x16x32_f16, 3 passes (hi*hi, hi*lo, lo*hi).
// R12 (1595 us, spill-free): TS=4, M-split (acc[2][4]=32 floats -- the RA's no-spill
// threshold), coalesced fragment-ordered B, launch_bounds(256,4).
// R13: B DOUBLE-BUFFER back on top. R12's JIT single-buffer B exposes ~200-300 cyc
// L2 latency per kb step (8 loads -> vmcnt stall -> 24 MFMAs); with 2 waves/SIMD the
// pipes sum (1595) instead of overlapping (max ~650). Prefetching kb+1 (64 B-regs,
// live only inside kloop -- NOT across the region boundary that triggers acc spills)
// hides it. Peak live ~115 regs <= 128 budget.

#define N_PTS 65536
#define HID   256
#define TS    4

typedef _Float16 half_t;
typedef __attribute__((ext_vector_type(8))) _Float16 half8;
typedef __attribute__((ext_vector_type(8))) short short8;
typedef __attribute__((ext_vector_type(4))) float floatx4;

#define J_HI   0
#define J_LO   32768              // 64 rows * 512 B per plane
#define STAGE  65536              // per-wave stage slots (13728 B) / head A' overlay (12288 B)
#define REDBUF (STAGE + 13728)    // 192 B head partials
#define LDS_BYTES (REDBUF + 384)  // 79648 B -> 2 blocks/CU

#define STG_STRIDE 66             // floats; 4*66 % 32 == 8 -> quads hit distinct bank sets
#define STG_WAVE   3432           // 13*66*4 bytes per wave slot

struct alignas(4) hpair { half_t a, b; };

__device__ __forceinline__ float fast_tanh(float x) {
    float e = __builtin_amdgcn_exp2f(x * 2.885390081777927f);
    return 1.f - 2.f * __builtin_amdgcn_rcpf(e + 1.f);
}

__device__ __forceinline__ void tanh_jet(const float* u, float* h) {
    const float f  = fast_tanh(u[0]);
    const float f1 = 1.f - f * f;
    const float f2 = -2.f * f * f1;
    const float f3 = -2.f * f1 * f1 + 4.f * f * f * f1;
    const float ux = u[1], uy = u[2], ut = u[3];
    const float uxx = u[4], uxy = u[5], uyy = u[6], uxt = u[7], uyt = u[8];
    h[0] = f;
    h[1] = f1 * ux;  h[2] = f1 * uy;  h[3] = f1 * ut;
    h[4] = f2 * ux * ux + f1 * uxx;
    h[5] = f2 * ux * uy + f1 * uxy;
    h[6] = f2 * uy * uy + f1 * uyy;
    h[7] = f2 * ux * ut + f1 * uxt;
    h[8] = f2 * uy * ut + f1 * uyt;
    h[9]  = f3 * ux * ux * ux + 3.f * f2 * ux * uxx + f1 * u[9];
    h[10] = f3 * ux * ux * uy + f2 * (uxx * uy + 2.f * uxy * ux) + f1 * u[10];
    h[11] = f3 * ux * uy * uy + f2 * (uyy * ux + 2.f * uxy * uy) + f1 * u[11];
    h[12] = f3 * uy * uy * uy + 3.f * f2 * uy * uyy + f1 * u[12];
}

__device__ __forceinline__ float red32(float v) {
    v += __shfl_xor(v, 16, 64);
    v += __shfl_xor(v, 8, 64);
    v += __shfl_xor(v, 4, 64);
    v += __shfl_xor(v, 2, 64);
    v += __shfl_xor(v, 1, 64);
    return v;
}

// ---- prep: split W2, W3, Wp1, Wd1 into f16 hi/lo planes, FRAGMENT-ORDERED ----
// (n,k) -> addr = ((ntile*8 + kb)*64 + q*16 + nl)*8 + e
__global__ void prep_w(const float* __restrict__ W2, const float* __restrict__ W3,
                       const float* __restrict__ Wp1, const float* __restrict__ Wd1,
                       half_t* __restrict__ ws) {
    int idx = blockIdx.x * 256 + threadIdx.x;
#pragma unroll
    for (int r = 0; r < 4; ++r) {
        int e = idx + r * 65536;
        int m = e >> 16, i = e & 65535;
        const float* src = (m == 0) ? W2 : (m == 1) ? W3 : (m == 2) ? Wp1 : Wd1;
        float w = src[i];
        half_t hi = (half_t)w;
        half_t lo = (half_t)(w - (float)hi);
        int n = i >> 8, k = i & 255;
        int addr = (((n >> 4) * 8 + (k >> 5)) * 64 + ((k >> 3) & 3) * 16 + (n & 15)) * 8
                   + (k & 7);
        ws[m * 131072 + addr] = hi;
        ws[m * 131072 + 65536 + addr] = lo;
    }
}

// coalesced fragment load: wave covers ntiles wave*4..+3; 1 KB contiguous per instr
__device__ __forceinline__ void load_B(const half_t* __restrict__ Bhi,
                                       const half_t* __restrict__ Blo,
                                       int wave, int lane, int kb,
                                       half8 (&Bh)[4], half8 (&Bl)[4]) {
#pragma unroll
    for (int nt = 0; nt < 4; ++nt) {
        int off = (((wave * 4 + nt) * 8 + kb) * 64 + lane) * 8;
        Bh[nt] = *(const half8*)(Bhi + off);
        Bl[nt] = *(const half8*)(Blo + off);
    }
}

// one kb step of one M-half: 2 JIT A-tile loads, 24 MFMAs
__device__ __forceinline__ void mfma_phase(const char* __restrict__ smem, int mt_base,
                                           int kb, int q, int nl,
                                           const half8 (&Bh)[4], const half8 (&Bl)[4],
                                           floatx4 (&acc)[2][4]) {
#pragma unroll
    for (int mt = 0; mt < 2; ++mt) {
        int m = (mt_base + mt) * 16 + nl;
        int pc = (((kb * 4 + q) ^ (m & 15)) << 4) + m * 512;
        half8 Ah = *(const half8*)(smem + J_HI + pc);
        half8 Al = *(const half8*)(smem + J_LO + pc);
#pragma unroll
        for (int nt = 0; nt < 4; ++nt) {
            acc[mt][nt] = __builtin_amdgcn_mfma_f32_16x16x32_f16(Ah, Bh[nt], acc[mt][nt], 0, 0, 0);
            acc[mt][nt] = __builtin_amdgcn_mfma_f32_16x16x32_f16(Ah, Bl[nt], acc[mt][nt], 0, 0, 0);
            acc[mt][nt] = __builtin_amdgcn_mfma_f32_16x16x32_f16(Al, Bh[nt], acc[mt][nt], 0, 0, 0);
        }
    }
}

// one M-half K-sweep: dual-plane B double-buffer (64 regs, kloop-local)
__device__ __forceinline__ void kloop(const char* __restrict__ smem,
                                      const half_t* __restrict__ Bhi,
                                      const half_t* __restrict__ Blo,
                                      int wave, int lane, int nl, int q, int mt_base,
                                      floatx4 (&acc)[2][4]) {
#pragma unroll
    for (int mt = 0; mt < 2; ++mt)
#pragma unroll
        for (int nt = 0; nt < 4; ++nt) acc[mt][nt] = floatx4{0.f, 0.f, 0.f, 0.f};

    half8 B0h[4], B0l[4], B1h[4], B1l[4];
    load_B(Bhi, Blo, wave, lane, 0, B0h, B0l);
#pragma unroll 1
    for (int kb = 0; kb < 8; kb += 2) {
        load_B(Bhi, Blo, wave, lane, kb + 1, B1h, B1l);
        mfma_phase(smem, mt_base, kb, q, nl, B0h, B0l, acc);
        if (kb + 2 < 8) load_B(Bhi, Blo, wave, lane, kb + 2, B0h, B0l);
        mfma_phase(smem, mt_base, kb + 1, q, nl, B1h, B1l, acc);
    }
}

// gather 13 comps per (sample,neuron) via per-wave LDS stage (wave-synchronous,
// in-order LDS -> no barrier), tanh_jet, write J' hi/lo in place. One M-half.
__device__ __forceinline__ void epilogue(char* __restrict__ smem,
                                         const float* __restrict__ bias,
                                         int wave, int lane, int q, int nl, int mt_base,
                                         floatx4 (&acc)[2][4]) {
    float* stg = (float*)(smem + STAGE + wave * STG_WAVE);
    const int n = wave * 64 + lane;
#pragma unroll 1
    for (int mt = 0; mt < 2; ++mt) {
#pragma unroll
        for (int nt = 0; nt < 4; ++nt)
#pragma unroll
            for (int r = 0; r < 4; ++r) {
                int c = q * 4 + r;
                if (c < 13) stg[c * STG_STRIDE + nt * 16 + nl] = acc[mt][nt][r];
            }
        float u[13], h[13];
#pragma unroll
        for (int c = 0; c < 13; ++c) u[c] = stg[c * STG_STRIDE + lane];
        u[0] += bias[n];
        tanh_jet(u, h);
#pragma unroll
        for (int c = 0; c < 13; ++c) {
            int m = (mt_base + mt) * 16 + c;
            int off = m * 512 + (((n >> 3) ^ (m & 15)) << 4) + ((n & 7) << 1);
            half_t hi = (half_t)h[c];
            *(half_t*)(smem + J_HI + off) = hi;
            *(half_t*)(smem + J_LO + off) = (half_t)(h[c] - (float)hi);
        }
    }
}

// one full layer: two M-half sweeps. Half h touches only J rows 32h..32h+31
// (samples 2h,2h+1), so epi(h0) runs concurrently with other waves' kloop(h1).
__device__ __forceinline__ void layer(char* __restrict__ smem,
                                      const half_t* __restrict__ Bhi,
                                      const half_t* __restrict__ Blo,
                                      const float* __restrict__ bias,
                                      int wave, int lane, int q, int nl,
                                      floatx4 (&acc)[2][4]) {
    kloop(smem, Bhi, Blo, wave, lane, nl, q, 0, acc);
    __syncthreads();                 // half-0 J reads done before epi(0) overwrites
    epilogue(smem, bias, wave, lane, q, nl, 0, acc);
    kloop(smem, Bhi, Blo, wave, lane, nl, q, 2, acc);
    __syncthreads();                 // half-1 J reads done before epi(2) overwrites
    epilogue(smem, bias, wave, lane, q, nl, 2, acc);
    __syncthreads();                 // publish new J
}

__global__ __launch_bounds__(256, 4) void pinn_mfma(
    const float* __restrict__ gx, const float* __restrict__ gy, const float* __restrict__ gt,
    const float* __restrict__ W1, const float* __restrict__ b1,
    const float* __restrict__ b2, const float* __restrict__ b3,
    const float* __restrict__ bp1, const float* __restrict__ Wp2,
    const float* __restrict__ bd1, const float* __restrict__ Wd2,
    const float* __restrict__ bd2,
    const float* __restrict__ lam1p, const float* __restrict__ lam2p,
    const half_t* __restrict__ wsw, float* __restrict__ out) {
    extern __shared__ char smem[];
    const int t = threadIdx.x;
    const int wave = t >> 6, lane = t & 63;
    const int q = lane >> 4, nl = lane & 15;
    const int base = blockIdx.x * TS;

    // ---------------- Layer 1: (x,y,t) -> J1 ----------------
#pragma unroll 1
    for (int ii = 0; ii < 2; ++ii) {
        int p = t * 2 + ii;                 // (sample, j-pair) 0..511
        int s = p >> 7, j = (p & 127) * 2;
        float qx = gx[base + s], qy = gy[base + s], qt = gt[base + s];
        float hv[2][13];
#pragma unroll
        for (int d = 0; d < 2; ++d) {
            int jj = j + d;
            float w0 = W1[3 * jj], w1 = W1[3 * jj + 1], w2 = W1[3 * jj + 2];
            float f = fast_tanh(w0 * qx + w1 * qy + w2 * qt + b1[jj]);
            float f1 = 1.f - f * f;
            float f2c = -2.f * f * f1;
            float f3c = -2.f * f1 * f1 + 4.f * f * f * f1;
            float* h = hv[d];
            h[0] = f; h[1] = f1 * w0; h[2] = f1 * w1; h[3] = f1 * w2;
            h[4] = f2c * w0 * w0; h[5] = f2c * w0 * w1; h[6] = f2c * w1 * w1;
            h[7] = f2c * w0 * w2; h[8] = f2c * w1 * w2;
            h[9]  = f3c * w0 * w0 * w0; h[10] = f3c * w0 * w0 * w1;
            h[11] = f3c * w0 * w1 * w1; h[12] = f3c * w1 * w1 * w1;
        }
#pragma unroll
        for (int c = 0; c < 13; ++c) {
            int m = s * 16 + c;
            int off = m * 512 + ((((j) >> 3) ^ (m & 15)) << 4) + ((j & 7) << 1);
            half_t hA = (half_t)hv[0][c], hB = (half_t)hv[1][c];
            *(hpair*)(smem + J_HI + off) = hpair{hA, hB};
            half_t lA = (half_t)(hv[0][c] - (float)hA);
            half_t lB = (half_t)(hv[1][c] - (float)hB);
            *(hpair*)(smem + J_LO + off) = hpair{lA, lB};
        }
    }
    __syncthreads();

    floatx4 acc[2][4];

    // ---------------- Layers 2, 3 ----------------
    layer(smem, wsw,          wsw + 65536,          b2, wave, lane, q, nl, acc);
    layer(smem, wsw + 131072, wsw + 131072 + 65536, b3, wave, lane, q, nl, acc);

    // ---------------- Data head (uses J3 comps 0..2) ----------------
    {
        // repack A'[sr = s*3+c][plane][k] into STAGE region (12 rows x 1024 B)
        {
            int s = t >> 5, g = t & 31;
            if (s < TS) {
#pragma unroll
                for (int c = 0; c < 3; ++c) {
                    int m = s * 16 + c, sr = s * 3 + c;
                    int so = m * 512 + ((g ^ (m & 15)) << 4);
                    int dc = (g ^ (sr & 15)) << 4;
                    *(short8*)(smem + STAGE + sr * 1024 + dc) =
                        *(const short8*)(smem + J_HI + so);
                    *(short8*)(smem + STAGE + sr * 1024 + 512 + dc) =
                        *(const short8*)(smem + J_LO + so);
                }
            }
        }
        __syncthreads();
        // single M-tile: logical row r = 4s+c (c<3) -> storage row 3s+c
        floatx4 hacc[4];
#pragma unroll
        for (int nt = 0; nt < 4; ++nt) hacc[nt] = floatx4{0.f, 0.f, 0.f, 0.f};
        const half_t* Dhi = wsw + 3 * 131072;
        const half_t* Dlo = Dhi + 65536;
        int sr = (nl >> 2) * 3 + (nl & 3);
        if ((nl & 3) == 3) sr = 0;          // comp-3 rows are dummies (C rows ignored)
        half8 B0h[4], B0l[4], B1h[4], B1l[4];
        load_B(Dhi, Dlo, wave, lane, 0, B0h, B0l);
#pragma unroll 1
        for (int kb = 0; kb < 8; kb += 2) {
            load_B(Dhi, Dlo, wave, lane, kb + 1, B1h, B1l);
#pragma unroll
            for (int ph = 0; ph < 2; ++ph) {
                int kc = kb + ph;
                const half8(&Bh)[4] = ph ? B1h : B0h;
                const half8(&Bl)[4] = ph ? B1l : B0l;
                int pc = ((kc * 4 + q) ^ (sr & 15)) << 4;
                half8 Ah = *(const half8*)(smem + STAGE + sr * 1024 + pc);
                half8 Al = *(const half8*)(smem + STAGE + sr * 1024 + 512 + pc);
#pragma unroll
                for (int nt = 0; nt < 4; ++nt) {
                    hacc[nt] = __builtin_amdgcn_mfma_f32_16x16x32_f16(Ah, Bh[nt], hacc[nt], 0, 0, 0);
                    hacc[nt] = __builtin_amdgcn_mfma_f32_16x16x32_f16(Ah, Bl[nt], hacc[nt], 0, 0, 0);
                    hacc[nt] = __builtin_amdgcn_mfma_f32_16x16x32_f16(Al, Bh[nt], hacc[nt], 0, 0, 0);
                }
                if (ph == 0 && kb + 2 < 8) load_B(Dhi, Dlo, wave, lane, kb + 2, B0h, B0l);
            }
        }
        __syncthreads();
        // head epilogue: C row = q*4 + reg; row 4s+c -> s=q, c=reg (0..2 used)
        {
            float pp = 0, up = 0, vp = 0;
#pragma unroll
            for (int nt = 0; nt < 4; ++nt) {
                int n = wave * 64 + nt * 16 + nl;
                floatx4 a = hacc[nt];
                float f = fast_tanh(a.x + bd1[n]);
                float f1 = 1.f - f * f;
                float hdx = f1 * a.y, hdy = f1 * a.z;
                float w0 = Wd2[n], w1 = Wd2[HID + n];
                pp += w1 * f;
                up += w0 * hdy;
                vp -= w0 * hdx;
            }
            float* rb = (float*)(smem + REDBUF);
#pragma unroll
            for (int msk = 1; msk < 16; msk <<= 1) {
                pp += __shfl_xor(pp, msk, 64);
                up += __shfl_xor(up, msk, 64);
                vp += __shfl_xor(vp, msk, 64);
            }
            if (nl == 0) {                  // sample s = q
                rb[(q * 4 + wave) * 3 + 0] = pp;
                rb[(q * 4 + wave) * 3 + 1] = up;
                rb[(q * 4 + wave) * 3 + 2] = vp;
            }
        }
        __syncthreads();
        if (t < TS) {
            const float* rb = (const float*)(smem + REDBUF);
            float P = 0, U = 0, V = 0;
#pragma unroll
            for (int w = 0; w < 4; ++w) {
                P += rb[(t * 4 + w) * 3 + 0];
                U += rb[(t * 4 + w) * 3 + 1];
                V += rb[(t * 4 + w) * 3 + 2];
            }
            out[0 * N_PTS + base + t] = P + bd2[1];
            out[1 * N_PTS + base + t] = U;
            out[2 * N_PTS + base + t] = V;
        }
    }

    // ---------------- PDE-head layer Wp1 ----------------
    layer(smem, wsw + 2 * 131072, wsw + 2 * 131072 + 65536, bp1, wave, lane, q, nl, acc);

    // ---------------- PDE reduction from J4 ----------------
    {
        int s = t >> 5, g = t & 31;
        if (s < TS) {
            float wr0[8], wr1[8];
#pragma unroll
            for (int i = 0; i < 8; ++i) {
                wr0[i] = Wp2[g + 32 * i];
                wr1[i] = Wp2[HID + g + 32 * i];
            }
            float S[13];
#pragma unroll
            for (int c = 0; c < 13; ++c) {
                int m = s * 16 + c;
                float p = 0.f;
#pragma unroll
                for (int i = 0; i < 8; ++i) {
                    int k = g + 32 * i;
                    int off = m * 512 + (((k >> 3) ^ (m & 15)) << 4) + ((k & 7) << 1);
                    float hvv = (float)*(const half_t*)(smem + J_HI + off) +
                                (float)*(const half_t*)(smem + J_LO + off);
                    p += hvv * wr0[i];
                }
                S[c] = red32(p);
            }
            float px = 0.f, py = 0.f;
#pragma unroll
            for (int i = 0; i < 8; ++i) {
                int k = g + 32 * i;
                int m1 = s * 16 + 1, m2 = s * 16 + 2;
                int o1 = m1 * 512 + (((k >> 3) ^ (m1 & 15)) << 4) + ((k & 7) << 1);
                int o2 = m2 * 512 + (((k >> 3) ^ (m2 & 15)) << 4) + ((k & 7) << 1);
                px += ((float)*(const half_t*)(smem + J_HI + o1) +
                       (float)*(const half_t*)(smem + J_LO + o1)) * wr1[i];
                py += ((float)*(const half_t*)(smem + J_HI + o2) +
                       (float)*(const half_t*)(smem + J_LO + o2)) * wr1[i];
            }
            px = red32(px);
            py = red32(py);
            if (g == 0) {
                const float lam1 = lam1p[0], lam2 = lam2p[0];
                const float u_ = S[2], v_ = -S[1];
                const float u_x = S[5], u_y = S[6], u_t = S[8];
                const float v_x = -S[4], v_y = -S[5], v_t = -S[7];
                const float u_xx = S[10], u_yy = S[12];
                const float v_xx = -S[9], v_yy = -S[11];
                const float f_ = lam1 * (u_t + u_ * u_x + v_ * u_y) + px - lam2 * (u_xx + u_yy);
                const float g_ = lam1 * (v_t + u_ * v_x + v_ * v_y) + py - lam2 * (v_xx + v_yy);
                out[3 * N_PTS + base + s] = f_;
                out[4 * N_PTS + base + s] = g_;
            }
        }
    }
}

extern "C" void kernel_launch(void* const* d_in, const int* in_sizes, int n_in,
                              void* d_out, int out_size, void* d_ws, size_t ws_size,
                              hipStream_t stream) {
    const float* x   = (const float*)d_in[0];
    const float* y   = (const float*)d_in[1];
    const float* tt  = (const float*)d_in[2];
    const float* W1  = (const float*)d_in[6];
    const float* b1  = (const float*)d_in[7];
    const float* W2  = (const float*)d_in[8];
    const float* b2  = (const float*)d_in[9];
    const float* W3  = (const float*)d_in[10];
    const float* b3  = (const float*)d_in[11];
    const float* Wp1 = (const float*)d_in[12];
    const float* bp1 = (const float*)d_in[13];
    const float* Wp2 = (const float*)d_in[14];
    const float* Wd1 = (const float*)d_in[16];
    const float* bd1 = (const float*)d_in[17];
    const float* Wd2 = (const float*)d_in[18];
    const float* bd2 = (const float*)d_in[19];
    const float* l1  = (const float*)d_in[20];
    const float* l2  = (const float*)d_in[21];
    float* out = (float*)d_out;
    half_t* wsw = (half_t*)d_ws;   // needs 4 * 256 KB = 1 MB

    prep_w<<<256, 256, 0, stream>>>(W2, W3, Wp1, Wd1, wsw);

    (void)hipFuncSetAttribute((const void*)pinn_mfma,
                              hipFuncAttributeMaxDynamicSharedMemorySize,
                              (int)LDS_BYTES);
    pinn_mfma<<<N_PTS / TS, 256, LDS_BYTES, stream>>>(
        x, y, tt, W1, b1, b2, b3, bp1, Wp2, bd1, Wd2, bd2, l1, l2, wsw, out);
}

// Round 14
// 1554.624 us; speedup vs baseline: 1.7833x; 1.7833x over previous
//
#include <hip/hip_runtime.h>

// MFMA split-FP16 jet-propagation PINN.
// Jet comps: 0:val 1:x 2:y 3:t 4:xx 5:xy 6:yy 7:xt 8:yt 9:xxx 10:xxy 11:xyy 12:yyy
// J in LDS: PACKED rows m = sample*13 + comp, k = hidden neuron; f16 hi+lo planes.
// Row layout: 32 chunks of 8 f16 (16 B); phys chunk = logical ^ (m&15)  (bank swizzle).
// Per layer: U = J * W^T via mfma_f32_16x16x32_f16, 3 passes (hi*hi, hi*lo, lo*hi).
// R14: 3 blocks/CU. R12 (1595 us) was latency-bound at 2 blocks/CU with JIT B loads
// (register prefetch is impossible: R13 proved the RA spills ANY B double-buffer).
// LDS diet: packed-13 rows (52 KB, R9-verified), shuffle-transpose epilogue (kills
// the 13.7 KB stage), head A read directly from J (kills the 12 KB repack) ->
// 53.4 KB -> 3 blocks/CU = 12 waves/CU, +50% TLP against the B-load latency.
// acc[2][4]=32 floats (the RA's no-spill threshold), launch_bounds(256,4).

#define N_PTS 65536
#define HID   256
#define TS    4

typedef _Float16 half_t;
typedef __attribute__((ext_vector_type(8))) _Float16 half8;
typedef __attribute__((ext_vector_type(4))) float floatx4;

#define J_HI   0
#define J_LO   26624              // 52 packed rows * 512 B per plane
#define REDBUF 53248              // 192 B head partials
#define LDS_BYTES (REDBUF + 192)  // 53440 B -> 3 blocks/CU (160320 <= 163840)

struct alignas(4) hpair { half_t a, b; };

__device__ __forceinline__ float fast_tanh(float x) {
    float e = __builtin_amdgcn_exp2f(x * 2.885390081777927f);
    return 1.f - 2.f * __builtin_amdgcn_rcpf(e + 1.f);
}

__device__ __forceinline__ void tanh_jet(const float* u, float* h) {
    const float f  = fast_tanh(u[0]);
    const float f1 = 1.f - f * f;
    const float f2 = -2.f * f * f1;
    const float f3 = -2.f * f1 * f1 + 4.f * f * f * f1;
    const float ux = u[1], uy = u[2], ut = u[3];
    const float uxx = u[4], uxy = u[5], uyy = u[6], uxt = u[7], uyt = u[8];
    h[0] = f;
    h[1] = f1 * ux;  h[2] = f1 * uy;  h[3] = f1 * ut;
    h[4] = f2 * ux * ux + f1 * uxx;
    h[5] = f2 * ux * uy + f1 * uxy;
    h[6] = f2 * uy * uy + f1 * uyy;
    h[7] = f2 * ux * ut + f1 * uxt;
    h[8] = f2 * uy * ut + f1 * uyt;
    h[9]  = f3 * ux * ux * ux + 3.f * f2 * ux * uxx + f1 * u[9];
    h[10] = f3 * ux * ux * uy + f2 * (uxx * uy + 2.f * uxy * ux) + f1 * u[10];
    h[11] = f3 * ux * uy * uy + f2 * (uyy * ux + 2.f * uxy * uy) + f1 * u[11];
    h[12] = f3 * uy * uy * uy + 3.f * f2 * uy * uyy + f1 * u[12];
}

// ---- prep: split W2, W3, Wp1, Wd1 into f16 hi/lo planes, FRAGMENT-ORDERED ----
// (n,k) -> addr = ((ntile*8 + kb)*64 + q*16 + nl)*8 + e  -> wave loads 1 KB contiguous
__global__ void prep_w(const float* __restrict__ W2, const float* __restrict__ W3,
                       const float* __restrict__ Wp1, const float* __restrict__ Wd1,
                       half_t* __restrict__ ws) {
    int idx = blockIdx.x * 256 + threadIdx.x;
#pragma unroll
    for (int r = 0; r < 4; ++r) {
        int e = idx + r * 65536;
        int m = e >> 16, i = e & 65535;
        const float* src = (m == 0) ? W2 : (m == 1) ? W3 : (m == 2) ? Wp1 : Wd1;
        float w = src[i];
        half_t hi = (half_t)w;
        half_t lo = (half_t)(w - (float)hi);
        int n = i >> 8, k = i & 255;
        int addr = (((n >> 4) * 8 + (k >> 5)) * 64 + ((k >> 3) & 3) * 16 + (n & 15)) * 8
                   + (k & 7);
        ws[m * 131072 + addr] = hi;
        ws[m * 131072 + 65536 + addr] = lo;
    }
}

// coalesced fragment load: wave covers ntiles wave*4..+3; 1 KB contiguous per instr
__device__ __forceinline__ void load_B(const half_t* __restrict__ Bhi,
                                       const half_t* __restrict__ Blo,
                                       int wave, int lane, int kb,
                                       half8 (&Bh)[4], half8 (&Bl)[4]) {
#pragma unroll
    for (int nt = 0; nt < 4; ++nt) {
        int off = (((wave * 4 + nt) * 8 + kb) * 64 + lane) * 8;
        Bh[nt] = *(const half8*)(Bhi + off);
        Bl[nt] = *(const half8*)(Blo + off);
    }
}

// one kb step of one M-half: 2 JIT A-tile loads (packed-13 rows, clamped), 24 MFMAs
__device__ __forceinline__ void mfma_phase(const char* __restrict__ smem, int mt_base,
                                           int kb, int q, int anl,
                                           const half8 (&Bh)[4], const half8 (&Bl)[4],
                                           floatx4 (&acc)[2][4]) {
#pragma unroll
    for (int mt = 0; mt < 2; ++mt) {
        int m = (mt_base + mt) * 13 + anl;
        int pc = (((kb * 4 + q) ^ (m & 15)) << 4) + m * 512;
        half8 Ah = *(const half8*)(smem + J_HI + pc);
        half8 Al = *(const half8*)(smem + J_LO + pc);
#pragma unroll
        for (int nt = 0; nt < 4; ++nt) {
            acc[mt][nt] = __builtin_amdgcn_mfma_f32_16x16x32_f16(Ah, Bh[nt], acc[mt][nt], 0, 0, 0);
            acc[mt][nt] = __builtin_amdgcn_mfma_f32_16x16x32_f16(Ah, Bl[nt], acc[mt][nt], 0, 0, 0);
            acc[mt][nt] = __builtin_amdgcn_mfma_f32_16x16x32_f16(Al, Bh[nt], acc[mt][nt], 0, 0, 0);
        }
    }
}

// one M-half K-sweep, JIT single-buffer B (the only spill-free shape; 12 waves/CU
// now hide the per-step vmcnt latency)
__device__ __forceinline__ void kloop(const char* __restrict__ smem,
                                      const half_t* __restrict__ Bhi,
                                      const half_t* __restrict__ Blo,
                                      int wave, int lane, int anl, int q, int mt_base,
                                      floatx4 (&acc)[2][4]) {
#pragma unroll
    for (int mt = 0; mt < 2; ++mt)
#pragma unroll
        for (int nt = 0; nt < 4; ++nt) acc[mt][nt] = floatx4{0.f, 0.f, 0.f, 0.f};
#pragma unroll 1
    for (int kb = 0; kb < 8; ++kb) {
        half8 Bh[4], Bl[4];
        load_B(Bhi, Blo, wave, lane, kb, Bh, Bl);
        mfma_phase(smem, mt_base, kb, q, anl, Bh, Bl, acc);
    }
}

// shuffle-transpose epilogue (no LDS stage): 4x4 transpose among lanes {q,same nl}
// via two shfl_xor butterflies; then tanh_jet; write J' hi/lo in place. One M-half.
__device__ __forceinline__ void epilogue(char* __restrict__ smem,
                                         const float* __restrict__ bias,
                                         int wave, int lane, int q, int mt_base,
                                         floatx4 (&acc)[2][4]) {
    const int n = wave * 64 + lane;
    const float bn = bias[n];
#pragma unroll
    for (int mt = 0; mt < 2; ++mt) {
        // stage 1 (xor bit0 of q <-> slot): a[j] = ((j^q)&1) ? partner16(v[j^1]) : v[j]
        float a0[4][4], e[4][4];
#pragma unroll
        for (int j = 0; j < 4; ++j)
#pragma unroll
            for (int r = 0; r < 4; ++r) {
                float part = __shfl_xor(acc[mt][j ^ 1][r], 16, 64);
                a0[j][r] = ((j ^ q) & 1) ? part : acc[mt][j][r];
            }
        // stage 2 (xor bit1): e[j] = ((j^q)&2) ? partner32(a[j^2]) : a[j]
#pragma unroll
        for (int j = 0; j < 4; ++j)
#pragma unroll
            for (int r = 0; r < 4; ++r) {
                float part = __shfl_xor(a0[j ^ 2][r], 32, 64);
                e[j][r] = ((j ^ q) & 2) ? part : a0[j][r];
            }
        // e[Q][R] = C row 4Q+R of column n
        float u[13], h[13];
#pragma unroll
        for (int c = 0; c < 13; ++c) u[c] = e[c >> 2][c & 3];
        u[0] += bn;
        tanh_jet(u, h);
#pragma unroll
        for (int c = 0; c < 13; ++c) {
            int m = (mt_base + mt) * 13 + c;
            int off = m * 512 + (((n >> 3) ^ (m & 15)) << 4) + ((n & 7) << 1);
            half_t hi = (half_t)h[c];
            *(half_t*)(smem + J_HI + off) = hi;
            *(half_t*)(smem + J_LO + off) = (half_t)(h[c] - (float)hi);
        }
    }
}

// one full layer: two M-half sweeps. Half h touches only J rows 26h..26h+25
// (samples 2h,2h+1), so epi(h0) runs concurrently with other waves' kloop(h1).
__device__ __forceinline__ void layer(char* __restrict__ smem,
                                      const half_t* __restrict__ Bhi,
                                      const half_t* __restrict__ Blo,
                                      const float* __restrict__ bias,
                                      int wave, int lane, int q, int anl,
                                      floatx4 (&acc)[2][4]) {
    kloop(smem, Bhi, Blo, wave, lane, anl, q, 0, acc);
    __syncthreads();                 // half-0 J reads done before epi(0) overwrites
    epilogue(smem, bias, wave, lane, q, 0, acc);
    kloop(smem, Bhi, Blo, wave, lane, anl, q, 2, acc);
    __syncthreads();                 // half-1 J reads done before epi(2) overwrites
    epilogue(smem, bias, wave, lane, q, 2, acc);
    __syncthreads();                 // publish new J
}

__global__ __launch_bounds__(256, 4) void pinn_mfma(
    const float* __restrict__ gx, const float* __restrict__ gy, const float* __restrict__ gt,
    const float* __restrict__ W1, const float* __restrict__ b1,
    const float* __restrict__ b2, const float* __restrict__ b3,
    const float* __restrict__ bp1, const float* __restrict__ Wp2,
    const float* __restrict__ bd1, const float* __restrict__ Wd2,
    const float* __restrict__ bd2,
    const float* __restrict__ lam1p, const float* __restrict__ lam2p,
    const half_t* __restrict__ wsw, float* __restrict__ out) {
    extern __shared__ char smem[];
    const int t = threadIdx.x;
    const int wave = t >> 6, lane = t & 63;
    const int q = lane >> 4, nl = lane & 15;
    const int anl = nl < 13 ? nl : 12;   // packed-13 row clamp (dup rows ignored in C)
    const int base = blockIdx.x * TS;

    // ---------------- Layer 1: (x,y,t) -> J1 ----------------
#pragma unroll 1
    for (int ii = 0; ii < 2; ++ii) {
        int p = t * 2 + ii;                 // (sample, j-pair) 0..511
        int s = p >> 7, j = (p & 127) * 2;
        float qx = gx[base + s], qy = gy[base + s], qt = gt[base + s];
        float hv[2][13];
#pragma unroll
        for (int d = 0; d < 2; ++d) {
            int jj = j + d;
            float w0 = W1[3 * jj], w1 = W1[3 * jj + 1], w2 = W1[3 * jj + 2];
            float f = fast_tanh(w0 * qx + w1 * qy + w2 * qt + b1[jj]);
            float f1 = 1.f - f * f;
            float f2c = -2.f * f * f1;
            float f3c = -2.f * f1 * f1 + 4.f * f * f * f1;
            float* h = hv[d];
            h[0] = f; h[1] = f1 * w0; h[2] = f1 * w1; h[3] = f1 * w2;
            h[4] = f2c * w0 * w0; h[5] = f2c * w0 * w1; h[6] = f2c * w1 * w1;
            h[7] = f2c * w0 * w2; h[8] = f2c * w1 * w2;
            h[9]  = f3c * w0 * w0 * w0; h[10] = f3c * w0 * w0 * w1;
            h[11] = f3c * w0 * w1 * w1; h[12] = f3c * w1 * w1 * w1;
        }
#pragma unroll
        for (int c = 0; c < 13; ++c) {
            int m = s * 13 + c;
            int off = m * 512 + ((((j) >> 3) ^ (m & 15)) << 4) + ((j & 7) << 1);
            half_t hA = (half_t)hv[0][c], hB = (half_t)hv[1][c];
            *(hpair*)(smem + J_HI + off) = hpair{hA, hB};
            half_t lA = (half_t)(hv[0][c] - (float)hA);
            half_t lB = (half_t)(hv[1][c] - (float)hB);
            *(hpair*)(smem + J_LO + off) = hpair{lA, lB};
        }
    }
    __syncthreads();

    floatx4 acc[2][4];

    // ---------------- Layers 2, 3 ----------------
    layer(smem, wsw,          wsw + 65536,          b2, wave, lane, q, anl, acc);
    layer(smem, wsw + 131072, wsw + 131072 + 65536, b3, wave, lane, q, anl, acc);

    // ---------------- Data head (uses J3 comps 0..2), A read directly from J ----
    {
        // single M-tile: logical row r = nl = 4s+c -> J row s*13+c (c<3; c==3 dummy)
        int sh = nl >> 2, ch = nl & 3;
        int mh = sh * 13 + ((ch == 3) ? 0 : ch);
        floatx4 hacc[4];
#pragma unroll
        for (int nt = 0; nt < 4; ++nt) hacc[nt] = floatx4{0.f, 0.f, 0.f, 0.f};
        const half_t* Dhi = wsw + 3 * 131072;
        const half_t* Dlo = Dhi + 65536;
#pragma unroll 1
        for (int kb = 0; kb < 8; ++kb) {
            half8 Bh[4], Bl[4];
            load_B(Dhi, Dlo, wave, lane, kb, Bh, Bl);
            int pc = (((kb * 4 + q) ^ (mh & 15)) << 4) + mh * 512;
            half8 Ah = *(const half8*)(smem + J_HI + pc);
            half8 Al = *(const half8*)(smem + J_LO + pc);
#pragma unroll
            for (int nt = 0; nt < 4; ++nt) {
                hacc[nt] = __builtin_amdgcn_mfma_f32_16x16x32_f16(Ah, Bh[nt], hacc[nt], 0, 0, 0);
                hacc[nt] = __builtin_amdgcn_mfma_f32_16x16x32_f16(Ah, Bl[nt], hacc[nt], 0, 0, 0);
                hacc[nt] = __builtin_amdgcn_mfma_f32_16x16x32_f16(Al, Bh[nt], hacc[nt], 0, 0, 0);
            }
        }
        // head epilogue: C row = q*4 + reg -> sample s = q, comp c = reg (0..2 used)
        {
            float pp = 0, up = 0, vp = 0;
#pragma unroll
            for (int nt = 0; nt < 4; ++nt) {
                int n = wave * 64 + nt * 16 + nl;
                floatx4 a = hacc[nt];
                float f = fast_tanh(a.x + bd1[n]);
                float f1 = 1.f - f * f;
                float hdx = f1 * a.y, hdy = f1 * a.z;
                float w0 = Wd2[n], w1 = Wd2[HID + n];
                pp += w1 * f;
                up += w0 * hdy;
                vp -= w0 * hdx;
            }
            float* rb = (float*)(smem + REDBUF);
#pragma unroll
            for (int msk = 1; msk < 16; msk <<= 1) {
                pp += __shfl_xor(pp, msk, 64);
                up += __shfl_xor(up, msk, 64);
                vp += __shfl_xor(vp, msk, 64);
            }
            if (nl == 0) {                  // sample s = q
                rb[(q * 4 + wave) * 3 + 0] = pp;
                rb[(q * 4 + wave) * 3 + 1] = up;
                rb[(q * 4 + wave) * 3 + 2] = vp;
            }
        }
        __syncthreads();
        if (t < TS) {
            const float* rb = (const float*)(smem + REDBUF);
            float P = 0, U = 0, V = 0;
#pragma unroll
            for (int w = 0; w < 4; ++w) {
                P += rb[(t * 4 + w) * 3 + 0];
                U += rb[(t * 4 + w) * 3 + 1];
                V += rb[(t * 4 + w) * 3 + 2];
            }
            out[0 * N_PTS + base + t] = P + bd2[1];
            out[1 * N_PTS + base + t] = U;
            out[2 * N_PTS + base + t] = V;
        }
    }

    // ---------------- PDE-head layer Wp1 ----------------
    layer(smem, wsw + 2 * 131072, wsw + 2 * 131072 + 65536, bp1, wave, lane, q, anl, acc);

    // ---------------- PDE reduction from J4 ----------------
    {
        int s = t >> 5, g = t & 31;
        if (s < TS) {
            float wr0[8], wr1[8];
#pragma unroll
            for (int i = 0; i < 8; ++i) {
                wr0[i] = Wp2[g + 32 * i];
                wr1[i] = Wp2[HID + g + 32 * i];
            }
            float S[13];
#pragma unroll
            for (int c = 0; c < 13; ++c) {
                int m = s * 13 + c;
                float p = 0.f;
#pragma unroll
                for (int i = 0; i < 8; ++i) {
                    int k = g + 32 * i;
                    int off = m * 512 + (((k >> 3) ^ (m & 15)) << 4) + ((k & 7) << 1);
                    float hvv = (float)*(const half_t*)(smem + J_HI + off) +
                                (float)*(const half_t*)(smem + J_LO + off);
                    p += hvv * wr0[i];
                }
#pragma unroll
                for (int msk = 1; msk < 32; msk <<= 1) p += __shfl_xor(p, msk, 64);
                S[c] = p;
            }
            float px = 0.f, py = 0.f;
#pragma unroll
            for (int i = 0; i < 8; ++i) {
                int k = g + 32 * i;
                int m1 = s * 13 + 1, m2 = s * 13 + 2;
                int o1 = m1 * 512 + (((k >> 3) ^ (m1 & 15)) << 4) + ((k & 7) << 1);
                int o2 = m2 * 512 + (((k >> 3) ^ (m2 & 15)) << 4) + ((k & 7) << 1);
                px += ((float)*(const half_t*)(smem + J_HI + o1) +
                       (float)*(const half_t*)(smem + J_LO + o1)) * wr1[i];
                py += ((float)*(const half_t*)(smem + J_HI + o2) +
                       (float)*(const half_t*)(smem + J_LO + o2)) * wr1[i];
            }
#pragma unroll
            for (int msk = 1; msk < 32; msk <<= 1) {
                px += __shfl_xor(px, msk, 64);
                py += __shfl_xor(py, msk, 64);
            }
            if (g == 0) {
                const float lam1 = lam1p[0], lam2 = lam2p[0];
                const float u_ = S[2], v_ = -S[1];
                const float u_x = S[5], u_y = S[6], u_t = S[8];
                const float v_x = -S[4], v_y = -S[5], v_t = -S[7];
                const float u_xx = S[10], u_yy = S[12];
                const float v_xx = -S[9], v_yy = -S[11];
                const float f_ = lam1 * (u_t + u_ * u_x + v_ * u_y) + px - lam2 * (u_xx + u_yy);
                const float g_ = lam1 * (v_t + u_ * v_x + v_ * v_y) + py - lam2 * (v_xx + v_yy);
                out[3 * N_PTS + base + s] = f_;
                out[4 * N_PTS + base + s] = g_;
            }
        }
    }
}

extern "C" void kernel_launch(void* const* d_in, const int* in_sizes, int n_in,
                              void* d_out, int out_size, void* d_ws, size_t ws_size,
                              hipStream_t stream) {
    const float* x   = (const float*)d_in[0];
    const float* y   = (const float*)d_in[1];
    const float* tt  = (const float*)d_in[2];
    const float* W1  = (const float*)d_in[6];
    const float* b1  = (const float*)d_in[7];
    const float* W2  = (const float*)d_in[8];
    const float* b2  = (const float*)d_in[9];
    const float* W3  = (const float*)d_in[10];
    const float* b3  = (const float*)d_in[11];
    const float* Wp1 = (const float*)d_in[12];
    const float* bp1 = (const float*)d_in[13];
    const float* Wp2 = (const float*)d_in[14];
    const float* Wd1 = (const float*)d_in[16];
    const float* bd1 = (const float*)d_in[17];
    const float* Wd2 = (const float*)d_in[18];
    const float* bd2 = (const float*)d_in[19];
    const float* l1  = (const float*)d_in[20];
    const float* l2  = (const float*)d_in[21];
    float* out = (float*)d_out;
    half_t* wsw = (half_t*)d_ws;   // needs 4 * 256 KB = 1 MB

    prep_w<<<256, 256, 0, stream>>>(W2, W3, Wp1, Wd1, wsw);

    (void)hipFuncSetAttribute((const void*)pinn_mfma,
                              hipFuncAttributeMaxDynamicSharedMemorySize,
                              (int)LDS_BYTES);
    pinn_mfma<<<N_PTS / TS, 256, LDS_BYTES, stream>>>(
        x, y, tt, W1, b1, b2, b3, bp1, Wp2, bd1, Wd2, bd2, l1, l2, wsw, out);
}

// Round 15
// 1552.466 us; speedup vs baseline: 1.7858x; 1.0014x over previous
//
#include <hip/hip_runtime.h>

// MFMA split-FP16 jet-propagation PINN.
// Jet comps: 0:val 1:x 2:y 3:t 4:xx 5:xy 6:yy 7:xt 8:yt 9:xxx 10:xxy 11:xyy 12:yyy
// J in LDS: PACKED rows m = sample*13 + comp, k = hidden neuron; f16 hi+lo planes.
// Row layout: 32 chunks of 8 f16 (16 B); phys chunk = logical ^ (m&15)  (bank swizzle).
// Per layer: U = J * W^T via mfma_f32_16x16x32_f16, 3 passes (hi*hi, hi*lo, lo*hi).
// R14 (1555 us): 3 blocks/CU, spill-free, MfmaUtil 45% + VALUBusy 51% ~= 97% ->
// work-bound, VALU is the larger pipe.
// R15: SCALARIZED B ADDRESSING. load_B's per-lane address chain (~1800 VALU/thread,
// the largest VALU block) is wave-uniform except lane*16: readfirstlane(wave) forces
// the base into SGPRs -> global_load with SGPR base + one constant per-lane VGPR
// offset; (nt,kb) terms become scalar adds (free vs the VALU pipe).

#define N_PTS 65536
#define HID   256
#define TS    4

typedef _Float16 half_t;
typedef __attribute__((ext_vector_type(8))) _Float16 half8;
typedef __attribute__((ext_vector_type(4))) float floatx4;

#define J_HI   0
#define J_LO   26624              // 52 packed rows * 512 B per plane
#define REDBUF 53248              // 192 B head partials
#define LDS_BYTES (REDBUF + 192)  // 53440 B -> 3 blocks/CU

struct alignas(4) hpair { half_t a, b; };

__device__ __forceinline__ float fast_tanh(float x) {
    float e = __builtin_amdgcn_exp2f(x * 2.885390081777927f);
    return 1.f - 2.f * __builtin_amdgcn_rcpf(e + 1.f);
}

__device__ __forceinline__ void tanh_jet(const float* u, float* h) {
    const float f  = fast_tanh(u[0]);
    const float f1 = 1.f - f * f;
    const float f2 = -2.f * f * f1;
    const float f3 = -2.f * f1 * f1 + 4.f * f * f * f1;
    const float ux = u[1], uy = u[2], ut = u[3];
    const float uxx = u[4], uxy = u[5], uyy = u[6], uxt = u[7], uyt = u[8];
    h[0] = f;
    h[1] = f1 * ux;  h[2] = f1 * uy;  h[3] = f1 * ut;
    h[4] = f2 * ux * ux + f1 * uxx;
    h[5] = f2 * ux * uy + f1 * uxy;
    h[6] = f2 * uy * uy + f1 * uyy;
    h[7] = f2 * ux * ut + f1 * uxt;
    h[8] = f2 * uy * ut + f1 * uyt;
    h[9]  = f3 * ux * ux * ux + 3.f * f2 * ux * uxx + f1 * u[9];
    h[10] = f3 * ux * ux * uy + f2 * (uxx * uy + 2.f * uxy * ux) + f1 * u[10];
    h[11] = f3 * ux * uy * uy + f2 * (uyy * ux + 2.f * uxy * uy) + f1 * u[11];
    h[12] = f3 * uy * uy * uy + 3.f * f2 * uy * uyy + f1 * u[12];
}

// ---- prep: split W2, W3, Wp1, Wd1 into f16 hi/lo planes, FRAGMENT-ORDERED ----
// (n,k) -> addr = ((ntile*8 + kb)*64 + q*16 + nl)*8 + e  -> wave loads 1 KB contiguous
__global__ void prep_w(const float* __restrict__ W2, const float* __restrict__ W3,
                       const float* __restrict__ Wp1, const float* __restrict__ Wd1,
                       half_t* __restrict__ ws) {
    int idx = blockIdx.x * 256 + threadIdx.x;
#pragma unroll
    for (int r = 0; r < 4; ++r) {
        int e = idx + r * 65536;
        int m = e >> 16, i = e & 65535;
        const float* src = (m == 0) ? W2 : (m == 1) ? W3 : (m == 2) ? Wp1 : Wd1;
        float w = src[i];
        half_t hi = (half_t)w;
        half_t lo = (half_t)(w - (float)hi);
        int n = i >> 8, k = i & 255;
        int addr = (((n >> 4) * 8 + (k >> 5)) * 64 + ((k >> 3) & 3) * 16 + (n & 15)) * 8
                   + (k & 7);
        ws[m * 131072 + addr] = hi;
        ws[m * 131072 + 65536 + addr] = lo;
    }
}

// coalesced fragment load, SCALAR base: bh/bl are wave-uniform (readfirstlane),
// vo = lane*8 halfs is the only per-lane term -> SGPR-base global_load.
__device__ __forceinline__ void load_B(const half_t* bh, const half_t* bl,
                                       int vo, int kb,
                                       half8 (&Bh)[4], half8 (&Bl)[4]) {
#pragma unroll
    for (int nt = 0; nt < 4; ++nt) {
        int off = nt * 4096 + kb * 512 + vo;   // halfs; nt,kb uniform
        Bh[nt] = *(const half8*)(bh + off);
        Bl[nt] = *(const half8*)(bl + off);
    }
}

// one kb step of one M-half: 2 JIT A-tile loads (packed-13 rows, clamped), 24 MFMAs
__device__ __forceinline__ void mfma_phase(const char* __restrict__ smem, int mt_base,
                                           int kb, int q, int anl,
                                           const half8 (&Bh)[4], const half8 (&Bl)[4],
                                           floatx4 (&acc)[2][4]) {
#pragma unroll
    for (int mt = 0; mt < 2; ++mt) {
        int m = (mt_base + mt) * 13 + anl;
        int pc = (((kb * 4 + q) ^ (m & 15)) << 4) + m * 512;
        half8 Ah = *(const half8*)(smem + J_HI + pc);
        half8 Al = *(const half8*)(smem + J_LO + pc);
#pragma unroll
        for (int nt = 0; nt < 4; ++nt) {
            acc[mt][nt] = __builtin_amdgcn_mfma_f32_16x16x32_f16(Ah, Bh[nt], acc[mt][nt], 0, 0, 0);
            acc[mt][nt] = __builtin_amdgcn_mfma_f32_16x16x32_f16(Ah, Bl[nt], acc[mt][nt], 0, 0, 0);
            acc[mt][nt] = __builtin_amdgcn_mfma_f32_16x16x32_f16(Al, Bh[nt], acc[mt][nt], 0, 0, 0);
        }
    }
}

// one M-half K-sweep, JIT single-buffer B (the only spill-free shape)
__device__ __forceinline__ void kloop(const char* __restrict__ smem,
                                      const half_t* bh, const half_t* bl,
                                      int vo, int anl, int q, int mt_base,
                                      floatx4 (&acc)[2][4]) {
#pragma unroll
    for (int mt = 0; mt < 2; ++mt)
#pragma unroll
        for (int nt = 0; nt < 4; ++nt) acc[mt][nt] = floatx4{0.f, 0.f, 0.f, 0.f};
#pragma unroll 1
    for (int kb = 0; kb < 8; ++kb) {
        half8 Bh[4], Bl[4];
        load_B(bh, bl, vo, kb, Bh, Bl);
        mfma_phase(smem, mt_base, kb, q, anl, Bh, Bl, acc);
    }
}

// shuffle-transpose epilogue (no LDS stage): 4x4 transpose among lanes {q,same nl}
// via two shfl_xor butterflies; then tanh_jet; write J' hi/lo in place. One M-half.
__device__ __forceinline__ void epilogue(char* __restrict__ smem,
                                         const float* __restrict__ bias,
                                         int wave, int lane, int q, int mt_base,
                                         floatx4 (&acc)[2][4]) {
    const int n = wave * 64 + lane;
    const float bn = bias[n];
#pragma unroll
    for (int mt = 0; mt < 2; ++mt) {
        float a0[4][4], e[4][4];
#pragma unroll
        for (int j = 0; j < 4; ++j)
#pragma unroll
            for (int r = 0; r < 4; ++r) {
                float part = __shfl_xor(acc[mt][j ^ 1][r], 16, 64);
                a0[j][r] = ((j ^ q) & 1) ? part : acc[mt][j][r];
            }
#pragma unroll
        for (int j = 0; j < 4; ++j)
#pragma unroll
            for (int r = 0; r < 4; ++r) {
                float part = __shfl_xor(a0[j ^ 2][r], 32, 64);
                e[j][r] = ((j ^ q) & 2) ? part : a0[j][r];
            }
        // e[Q][R] = C row 4Q+R of column n
        float u[13], h[13];
#pragma unroll
        for (int c = 0; c < 13; ++c) u[c] = e[c >> 2][c & 3];
        u[0] += bn;
        tanh_jet(u, h);
#pragma unroll
        for (int c = 0; c < 13; ++c) {
            int m = (mt_base + mt) * 13 + c;
            int off = m * 512 + (((n >> 3) ^ (m & 15)) << 4) + ((n & 7) << 1);
            half_t hi = (half_t)h[c];
            *(half_t*)(smem + J_HI + off) = hi;
            *(half_t*)(smem + J_LO + off) = (half_t)(h[c] - (float)hi);
        }
    }
}

// one full layer: two M-half sweeps. Half h touches only J rows 26h..26h+25
// (samples 2h,2h+1), so epi(h0) runs concurrently with other waves' kloop(h1).
__device__ __forceinline__ void layer(char* __restrict__ smem,
                                      const half_t* bh, const half_t* bl,
                                      const float* __restrict__ bias,
                                      int wave, int lane, int vo, int q, int anl,
                                      floatx4 (&acc)[2][4]) {
    kloop(smem, bh, bl, vo, anl, q, 0, acc);
    __syncthreads();                 // half-0 J reads done before epi(0) overwrites
    epilogue(smem, bias, wave, lane, q, 0, acc);
    kloop(smem, bh, bl, vo, anl, q, 2, acc);
    __syncthreads();                 // half-1 J reads done before epi(2) overwrites
    epilogue(smem, bias, wave, lane, q, 2, acc);
    __syncthreads();                 // publish new J
}

__global__ __launch_bounds__(256, 4) void pinn_mfma(
    const float* __restrict__ gx, const float* __restrict__ gy, const float* __restrict__ gt,
    const float* __restrict__ W1, const float* __restrict__ b1,
    const float* __restrict__ b2, const float* __restrict__ b3,
    const float* __restrict__ bp1, const float* __restrict__ Wp2,
    const float* __restrict__ bd1, const float* __restrict__ Wd2,
    const float* __restrict__ bd2,
    const float* __restrict__ lam1p, const float* __restrict__ lam2p,
    const half_t* __restrict__ wsw, float* __restrict__ out) {
    extern __shared__ char smem[];
    const int t = threadIdx.x;
    const int wave = t >> 6, lane = t & 63;
    const int q = lane >> 4, nl = lane & 15;
    const int anl = nl < 13 ? nl : 12;   // packed-13 row clamp (dup rows ignored in C)
    const int base = blockIdx.x * TS;
    // wave-uniform B base offset (halfs) + per-lane offset: scalarized addressing
    const int wo = __builtin_amdgcn_readfirstlane(wave) * 16384;
    const int vo = lane * 8;

    // ---------------- Layer 1: (x,y,t) -> J1 ----------------
#pragma unroll 1
    for (int ii = 0; ii < 2; ++ii) {
        int p = t * 2 + ii;                 // (sample, j-pair) 0..511
        int s = p >> 7, j = (p & 127) * 2;
        float qx = gx[base + s], qy = gy[base + s], qt = gt[base + s];
        float hv[2][13];
#pragma unroll
        for (int d = 0; d < 2; ++d) {
            int jj = j + d;
            float w0 = W1[3 * jj], w1 = W1[3 * jj + 1], w2 = W1[3 * jj + 2];
            float f = fast_tanh(w0 * qx + w1 * qy + w2 * qt + b1[jj]);
            float f1 = 1.f - f * f;
            float f2c = -2.f * f * f1;
            float f3c = -2.f * f1 * f1 + 4.f * f * f * f1;
            float* h = hv[d];
            h[0] = f; h[1] = f1 * w0; h[2] = f1 * w1; h[3] = f1 * w2;
            h[4] = f2c * w0 * w0; h[5] = f2c * w0 * w1; h[6] = f2c * w1 * w1;
            h[7] = f2c * w0 * w2; h[8] = f2c * w1 * w2;
            h[9]  = f3c * w0 * w0 * w0; h[10] = f3c * w0 * w0 * w1;
            h[11] = f3c * w0 * w1 * w1; h[12] = f3c * w1 * w1 * w1;
        }
#pragma unroll
        for (int c = 0; c < 13; ++c) {
            int m = s * 13 + c;
            int off = m * 512 + ((((j) >> 3) ^ (m & 15)) << 4) + ((j & 7) << 1);
            half_t hA = (half_t)hv[0][c], hB = (half_t)hv[1][c];
            *(hpair*)(smem + J_HI + off) = hpair{hA, hB};
            half_t lA = (half_t)(hv[0][c] - (float)hA);
            half_t lB = (half_t)(hv[1][c] - (float)hB);
            *(hpair*)(smem + J_LO + off) = hpair{lA, lB};
        }
    }
    __syncthreads();

    floatx4 acc[2][4];

    // ---------------- Layers 2, 3 ----------------
    layer(smem, wsw + wo,          wsw + 65536 + wo,          b2,
          wave, lane, vo, q, anl, acc);
    layer(smem, wsw + 131072 + wo, wsw + 131072 + 65536 + wo, b3,
          wave, lane, vo, q, anl, acc);

    // ---------------- Data head (uses J3 comps 0..2), A read directly from J ----
    {
        // single M-tile: logical row r = nl = 4s+c -> J row s*13+c (c<3; c==3 dummy)
        int sh = nl >> 2, ch = nl & 3;
        int mh = sh * 13 + ((ch == 3) ? 0 : ch);
        floatx4 hacc[4];
#pragma unroll
        for (int nt = 0; nt < 4; ++nt) hacc[nt] = floatx4{0.f, 0.f, 0.f, 0.f};
        const half_t* Dhi = wsw + 3 * 131072 + wo;
        const half_t* Dlo = Dhi + 65536;
#pragma unroll 1
        for (int kb = 0; kb < 8; ++kb) {
            half8 Bh[4], Bl[4];
            load_B(Dhi, Dlo, vo, kb, Bh, Bl);
            int pc = (((kb * 4 + q) ^ (mh & 15)) << 4) + mh * 512;
            half8 Ah = *(const half8*)(smem + J_HI + pc);
            half8 Al = *(const half8*)(smem + J_LO + pc);
#pragma unroll
            for (int nt = 0; nt < 4; ++nt) {
                hacc[nt] = __builtin_amdgcn_mfma_f32_16x16x32_f16(Ah, Bh[nt], hacc[nt], 0, 0, 0);
                hacc[nt] = __builtin_amdgcn_mfma_f32_16x16x32_f16(Ah, Bl[nt], hacc[nt], 0, 0, 0);
                hacc[nt] = __builtin_amdgcn_mfma_f32_16x16x32_f16(Al, Bh[nt], hacc[nt], 0, 0, 0);
            }
        }
        // head epilogue: C row = q*4 + reg -> sample s = q, comp c = reg (0..2 used)
        {
            float pp = 0, up = 0, vp = 0;
#pragma unroll
            for (int nt = 0; nt < 4; ++nt) {
                int n = wave * 64 + nt * 16 + nl;
                floatx4 a = hacc[nt];
                float f = fast_tanh(a.x + bd1[n]);
                float f1 = 1.f - f * f;
                float hdx = f1 * a.y, hdy = f1 * a.z;
                float w0 = Wd2[n], w1 = Wd2[HID + n];
                pp += w1 * f;
                up += w0 * hdy;
                vp -= w0 * hdx;
            }
            float* rb = (float*)(smem + REDBUF);
#pragma unroll
            for (int msk = 1; msk < 16; msk <<= 1) {
                pp += __shfl_xor(pp, msk, 64);
                up += __shfl_xor(up, msk, 64);
                vp += __shfl_xor(vp, msk, 64);
            }
            if (nl == 0) {                  // sample s = q
                rb[(q * 4 + wave) * 3 + 0] = pp;
                rb[(q * 4 + wave) * 3 + 1] = up;
                rb[(q * 4 + wave) * 3 + 2] = vp;
            }
        }
        __syncthreads();
        if (t < TS) {
            const float* rb = (const float*)(smem + REDBUF);
            float P = 0, U = 0, V = 0;
#pragma unroll
            for (int w = 0; w < 4; ++w) {
                P += rb[(t * 4 + w) * 3 + 0];
                U += rb[(t * 4 + w) * 3 + 1];
                V += rb[(t * 4 + w) * 3 + 2];
            }
            out[0 * N_PTS + base + t] = P + bd2[1];
            out[1 * N_PTS + base + t] = U;
            out[2 * N_PTS + base + t] = V;
        }
    }

    // ---------------- PDE-head layer Wp1 ----------------
    layer(smem, wsw + 2 * 131072 + wo, wsw + 2 * 131072 + 65536 + wo, bp1,
          wave, lane, vo, q, anl, acc);

    // ---------------- PDE reduction from J4 ----------------
    {
        int s = t >> 5, g = t & 31;
        if (s < TS) {
            float wr0[8], wr1[8];
#pragma unroll
            for (int i = 0; i < 8; ++i) {
                wr0[i] = Wp2[g + 32 * i];
                wr1[i] = Wp2[HID + g + 32 * i];
            }
            float S[13];
#pragma unroll
            for (int c = 0; c < 13; ++c) {
                int m = s * 13 + c;
                float p = 0.f;
#pragma unroll
                for (int i = 0; i < 8; ++i) {
                    int k = g + 32 * i;
                    int off = m * 512 + (((k >> 3) ^ (m & 15)) << 4) + ((k & 7) << 1);
                    float hvv = (float)*(const half_t*)(smem + J_HI + off) +
                                (float)*(const half_t*)(smem + J_LO + off);
                    p += hvv * wr0[i];
                }
#pragma unroll
                for (int msk = 1; msk < 32; msk <<= 1) p += __shfl_xor(p, msk, 64);
                S[c] = p;
            }
            float px = 0.f, py = 0.f;
#pragma unroll
            for (int i = 0; i < 8; ++i) {
                int k = g + 32 * i;
                int m1 = s * 13 + 1, m2 = s * 13 + 2;
                int o1 = m1 * 512 + (((k >> 3) ^ (m1 & 15)) << 4) + ((k & 7) << 1);
                int o2 = m2 * 512 + (((k >> 3) ^ (m2 & 15)) << 4) + ((k & 7) << 1);
                px += ((float)*(const half_t*)(smem + J_HI + o1) +
                       (float)*(const half_t*)(smem + J_LO + o1)) * wr1[i];
                py += ((float)*(const half_t*)(smem + J_HI + o2) +
                       (float)*(const half_t*)(smem + J_LO + o2)) * wr1[i];
            }
#pragma unroll
            for (int msk = 1; msk < 32; msk <<= 1) {
                px += __shfl_xor(px, msk, 64);
                py += __shfl_xor(py, msk, 64);
            }
            if (g == 0) {
                const float lam1 = lam1p[0], lam2 = lam2p[0];
                const float u_ = S[2], v_ = -S[1];
                const float u_x = S[5], u_y = S[6], u_t = S[8];
                const float v_x = -S[4], v_y = -S[5], v_t = -S[7];
                const float u_xx = S[10], u_yy = S[12];
                const float v_xx = -S[9], v_yy = -S[11];
                const float f_ = lam1 * (u_t + u_ * u_x + v_ * u_y) + px - lam2 * (u_xx + u_yy);
                const float g_ = lam1 * (v_t + u_ * v_x + v_ * v_y) + py - lam2 * (v_xx + v_yy);
                out[3 * N_PTS + base + s] = f_;
                out[4 * N_PTS + base + s] = g_;
            }
        }
    }
}

extern "C" void kernel_launch(void* const* d_in, const int* in_sizes, int n_in,
                              void* d_out, int out_size, void* d_ws, size_t ws_size,
                              hipStream_t stream) {
    const float* x   = (const float*)d_in[0];
    const float* y   = (const float*)d_in[1];
    const float* tt  = (const float*)d_in[2];
    const float* W1  = (const float*)d_in[6];
    const float* b1  = (const float*)d_in[7];
    const float* W2  = (const float*)d_in[8];
    const float* b2  = (const float*)d_in[9];
    const float* W3  = (const float*)d_in[10];
    const float* b3  = (const float*)d_in[11];
    const float* Wp1 = (const float*)d_in[12];
    const float* bp1 = (const float*)d_in[13];
    const float* Wp2 = (const float*)d_in[14];
    const float* Wd1 = (const float*)d_in[16];
    const float* bd1 = (const float*)d_in[17];
    const float* Wd2 = (const float*)d_in[18];
    const float* bd2 = (const float*)d_in[19];
    const float* l1  = (const float*)d_in[20];
    const float* l2  = (const float*)d_in[21];
    float* out = (float*)d_out;
    half_t* wsw = (half_t*)d_ws;   // needs 4 * 256 KB = 1 MB

    prep_w<<<256, 256, 0, stream>>>(W2, W3, Wp1, Wd1, wsw);

    (void)hipFuncSetAttribute((const void*)pinn_mfma,
                              hipFuncAttributeMaxDynamicSharedMemorySize,
                              (int)LDS_BYTES);
    pinn_mfma<<<N_PTS / TS, 256, LDS_BYTES, stream>>>(
        x, y, tt, W1, b1, b2, b3, bp1, Wp2, bd1, Wd2, bd2, l1, l2, wsw, out);
}